// Round 12
// baseline (38.756 us; speedup 1.0000x reference)
//
#include <hip/hip_runtime.h>
#include <math.h>

// LSTM_8589935226: B=4194304 independent LSTMs, T=4, I=1, H=2, C=1.
// Round 12: ALL activations via LDS tables — zero transcendentals.
//  - sig table: 2048 x f32, domain [-8,8), map (x128,+1024.5) folded in weights
//  - tanh table: 4096 x f32, domain [-8,8), g-row map (x256,+2048.5+2048base)
//    folded in weights; c lookup = 1 fma + cvt. No clamps (bounds proven).
//  - 24 KB LDS, 1024-thread blocks -> 2 blocks/CU = 100% theoretical occupancy
//    (R10's all-table failure was 32KB/35% occupancy, not the tables).
// Model: ~740 issue cyc/wave (R11 ~1500); LDS floor ~53k cyc/CU -> 29-33 us.

#define SIG_OFF  1024.5f
#define TANH_OFF 4096.5f   // 2048 (table base) + 2048 (center) + 0.5 (round)

// ws float layout: [0..7] wi, [8..15] wh0, [16..23] wh1, [24..31] bb,
// [32..34] fc, [64..2111] sig table, [2112..6207] tanh table
__global__ void lstm_prep(const float* __restrict__ W_ih,
                          const float* __restrict__ W_hh,
                          const float* __restrict__ b_ih,
                          const float* __restrict__ b_hh,
                          const float* __restrict__ W_fc,
                          const float* __restrict__ b_fc,
                          float* __restrict__ ws)
{
    const int k = threadIdx.x;
    if (k < 8) {
        // gate rows: i(0,1) f(2,3) g(4,5) o(6,7)
        if (k == 4 || k == 5) {        // g rows -> tanh table index domain
            ws[k]      = W_ih[k] * 256.0f;
            ws[8 + k]  = W_hh[2 * k] * 256.0f;
            ws[16 + k] = W_hh[2 * k + 1] * 256.0f;
            ws[24 + k] = (b_ih[k] + b_hh[k]) * 256.0f + TANH_OFF;
        } else {                       // sigmoid rows -> sig table index domain
            ws[k]      = W_ih[k] * 128.0f;
            ws[8 + k]  = W_hh[2 * k] * 128.0f;
            ws[16 + k] = W_hh[2 * k + 1] * 128.0f;
            ws[24 + k] = (b_ih[k] + b_hh[k]) * 128.0f + SIG_OFF;
        }
    } else if (k == 8) {
        ws[32] = W_fc[0]; ws[33] = W_fc[1]; ws[34] = b_fc[0];
    }
    for (int j = threadIdx.x; j < 2048; j += 256) {
        const float v = (float)(j - 1024) * (1.0f / 128.0f);   // [-8,8)
        ws[64 + j] = 1.0f / (1.0f + expf(-v));
    }
    for (int j = threadIdx.x; j < 4096; j += 256) {
        const float w = (float)(j - 2048) * (1.0f / 256.0f);   // [-8,8)
        ws[64 + 2048 + j] = tanhf(w);
    }
}

// all maps pre-folded: pre-activation IS the (fractional) table index
#define LUT(p) tbl[(int)(p)]

__device__ __forceinline__ float lstm_elem(const float4 xv,
                                           const float* __restrict__ tbl,
                                           const float* __restrict__ wi,
                                           const float* __restrict__ wh0,
                                           const float* __restrict__ wh1,
                                           const float* __restrict__ bb,
                                           float wf0, float wf1, float bf)
{
    float h0, h1, c0, c1;   // c in TRUE domain (|c| <= 4.03)

    // ---- t = 0: h=c=0 -> f-gate dead, gates affine in x0 ----
    {
        const float x0 = xv.x;
        const float I0 = LUT(fmaf(x0, wi[0], bb[0]));
        const float I1 = LUT(fmaf(x0, wi[1], bb[1]));
        const float G0 = LUT(fmaf(x0, wi[4], bb[4]));
        const float G1 = LUT(fmaf(x0, wi[5], bb[5]));
        const float O0 = LUT(fmaf(x0, wi[6], bb[6]));
        const float O1 = LUT(fmaf(x0, wi[7], bb[7]));
        c0 = I0 * G0;
        c1 = I1 * G1;
        h0 = O0 * LUT(fmaf(c0, 256.0f, TANH_OFF));
        h1 = O1 * LUT(fmaf(c1, 256.0f, TANH_OFF));
    }

    // ---- t = 1..3 ----
    const float xs[3] = {xv.y, xv.z, xv.w};
#pragma unroll
    for (int t = 0; t < 3; ++t) {
        const float xt = xs[t];
        const float p0 = fmaf(xt, wi[0], fmaf(h0, wh0[0], fmaf(h1, wh1[0], bb[0])));
        const float p1 = fmaf(xt, wi[1], fmaf(h0, wh0[1], fmaf(h1, wh1[1], bb[1])));
        const float p2 = fmaf(xt, wi[2], fmaf(h0, wh0[2], fmaf(h1, wh1[2], bb[2])));
        const float p3 = fmaf(xt, wi[3], fmaf(h0, wh0[3], fmaf(h1, wh1[3], bb[3])));
        const float p4 = fmaf(xt, wi[4], fmaf(h0, wh0[4], fmaf(h1, wh1[4], bb[4])));
        const float p5 = fmaf(xt, wi[5], fmaf(h0, wh0[5], fmaf(h1, wh1[5], bb[5])));
        const float p6 = fmaf(xt, wi[6], fmaf(h0, wh0[6], fmaf(h1, wh1[6], bb[6])));
        const float p7 = fmaf(xt, wi[7], fmaf(h0, wh0[7], fmaf(h1, wh1[7], bb[7])));
        const float I0 = LUT(p0), I1 = LUT(p1);
        const float F0 = LUT(p2), F1 = LUT(p3);
        const float G0 = LUT(p4), G1 = LUT(p5);
        const float O0 = LUT(p6), O1 = LUT(p7);
        c0 = fmaf(F0, c0, I0 * G0);
        c1 = fmaf(F1, c1, I1 * G1);
        h0 = O0 * LUT(fmaf(c0, 256.0f, TANH_OFF));
        h1 = O1 * LUT(fmaf(c1, 256.0f, TANH_OFF));
    }

    return fmaf(h0, wf0, fmaf(h1, wf1, bf));
}

__global__ __launch_bounds__(1024) void lstm_main(
    const float4* __restrict__ x,   // [B] float4 per element
    const float*  __restrict__ ws,  // preprocessed constants + tables
    float2* __restrict__ out,       // [B/2]
    int B2)
{
    __shared__ __align__(16) float tbl[6144];   // 24 KB: sig 2048 + tanh 4096
    const int tid = threadIdx.x;

    // cooperative table load: 6144 floats = 1536 float4 over 1024 threads
    {
        const float4* src = (const float4*)(ws + 64);
        float4* dst = (float4*)tbl;
        dst[tid] = src[tid];
        if (tid < 512) dst[tid + 1024] = src[tid + 1024];
    }

    // uniform weights -> scalar loads (overlap with table load)
    float wi[8], wh0[8], wh1[8], bb[8];
#pragma unroll
    for (int k = 0; k < 8; ++k) {
        wi[k] = ws[k]; wh0[k] = ws[8 + k]; wh1[k] = ws[16 + k]; bb[k] = ws[24 + k];
    }
    const float wf0 = ws[32], wf1 = ws[33], bf = ws[34];

    __syncthreads();

    const int idx = blockIdx.x * 1024 + tid;
    if (idx >= B2) return;

    const float4 xa = x[2 * idx];
    const float4 xb = x[2 * idx + 1];

    const float oa = lstm_elem(xa, tbl, wi, wh0, wh1, bb, wf0, wf1, bf);
    const float ob = lstm_elem(xb, tbl, wi, wh0, wh1, bb, wf0, wf1, bf);

    float2 o; o.x = oa; o.y = ob;
    out[idx] = o;
}

extern "C" void kernel_launch(void* const* d_in, const int* in_sizes, int n_in,
                              void* d_out, int out_size, void* d_ws, size_t ws_size,
                              hipStream_t stream)
{
    const float* W_ih = (const float*)d_in[1];
    const float* W_hh = (const float*)d_in[2];
    const float* b_ih = (const float*)d_in[3];
    const float* b_hh = (const float*)d_in[4];
    const float* W_fc = (const float*)d_in[5];
    const float* b_fc = (const float*)d_in[6];
    float* ws = (float*)d_ws;

    lstm_prep<<<1, 256, 0, stream>>>(W_ih, W_hh, b_ih, b_hh, W_fc, b_fc, ws);

    const float4* x = (const float4*)d_in[0];
    float2* out = (float2*)d_out;
    const int B = in_sizes[0] / 4;   // 4194304
    const int B2 = B / 2;            // 2097152
    const int threads = 1024;
    const int blocks = (B2 + threads - 1) / threads;   // 2048
    lstm_main<<<blocks, threads, 0, stream>>>(x, ws, out, B2);
}

// Round 13
// 33.924 us; speedup vs baseline: 1.1424x; 1.1424x over previous
//
#include <hip/hip_runtime.h>
#include <math.h>

// LSTM_8589935226: B=4194304 independent LSTMs, T=4, I=1, H=2, C=1.
// Round 13 = R11 (best, 36.4us: sig->LDS table w/ folded map, tanh->exp2+
// paired rcp) + t0 COLLAPSED: with h=c=0 and I=1, (h,c) after t=0 is a 1-D
// function of x0 -> 512-node float4 lerp table (h0,h1,c0s,c1s; c pre-scaled
// by 2*log2e for the exp2-tanh path). t0 cost: ~30V+6T+4DS -> ~11V+2DS.
// R12 lesson: all-table saturates the LDS pipe; R11's hybrid balances pipes.

__device__ __forceinline__ float fexp2(float x) { return __builtin_amdgcn_exp2f(x); }
__device__ __forceinline__ float frcp(float x)  { return __builtin_amdgcn_rcpf(x); }

#define S2C  2.8853900817779268f   // 2*log2(e)
#define TS   128.0f                // sig table scale
#define TOFF 1024.5f               // sig table center + nearest-round 0.5
// t0 table: 512 nodes over [-6.5, 6.5]; map u = x0*TMS + 256
#define TMS  39.384615384615387f   // 512/13

// ws float layout: [0..7] wi, [8..15] wh0, [16..23] wh1, [24..31] bb,
// [32..34] fc, [64..2111] sig table, [2112..4163] t0 table (513 float4,
// entry 512 duplicated so lerp j+1 read never overruns)
__global__ void lstm_prep(const float* __restrict__ W_ih,
                          const float* __restrict__ W_hh,
                          const float* __restrict__ b_ih,
                          const float* __restrict__ b_hh,
                          const float* __restrict__ W_fc,
                          const float* __restrict__ b_fc,
                          float* __restrict__ ws)
{
    const int k = threadIdx.x;
    if (k < 8) {
        // gate rows: i(0,1) f(2,3) g(4,5) o(6,7)
        if (k == 4 || k == 5) {        // g rows: exp2 path, scale 2*log2e
            ws[k]      = W_ih[k] * S2C;
            ws[8 + k]  = W_hh[2 * k] * S2C;
            ws[16 + k] = W_hh[2 * k + 1] * S2C;
            ws[24 + k] = (b_ih[k] + b_hh[k]) * S2C;
        } else {                       // sigmoid rows: table-map folded
            ws[k]      = W_ih[k] * TS;
            ws[8 + k]  = W_hh[2 * k] * TS;
            ws[16 + k] = W_hh[2 * k + 1] * TS;
            ws[24 + k] = (b_ih[k] + b_hh[k]) * TS + TOFF;
        }
    } else if (k == 8) {
        ws[32] = W_fc[0]; ws[33] = W_fc[1]; ws[34] = b_fc[0];
    }
    // sigmoid value table
    for (int j = threadIdx.x; j < 2048; j += 256) {
        const float v = (float)(j - 1024) * (1.0f / 128.0f);  // [-8,8)
        ws[64 + j] = 1.0f / (1.0f + expf(-v));
    }
    // t0 state table: exact t=0 LSTM step as a function of x0
    for (int j = threadIdx.x; j < 513; j += 256) {
        const int jj = (j < 512) ? j : 512;
        const float x0 = -6.5f + (float)jj * (13.0f / 512.0f);
        float hh[2], cc[2];
        for (int q = 0; q < 2; ++q) {
            const float pi = W_ih[q]     * x0 + b_ih[q]     + b_hh[q];
            const float pg = W_ih[4 + q] * x0 + b_ih[4 + q] + b_hh[4 + q];
            const float po = W_ih[6 + q] * x0 + b_ih[6 + q] + b_hh[6 + q];
            const float I = 1.0f / (1.0f + expf(-pi));
            const float G = tanhf(pg);
            const float O = 1.0f / (1.0f + expf(-po));
            cc[q] = I * G;
            hh[q] = O * tanhf(cc[q]);
        }
        ws[2112 + 4 * j]     = hh[0];
        ws[2112 + 4 * j + 1] = hh[1];
        ws[2112 + 4 * j + 2] = cc[0] * S2C;   // scaled-domain c
        ws[2112 + 4 * j + 3] = cc[1] * S2C;
    }
}

// sigmoid lookup: pre-act already carries the map (x128 + 1024.5)
#define SIG(p) tbl[(int)(p)]

__device__ __forceinline__ float lstm_elem(const float4 xv,
                                           const float* __restrict__ tbl,
                                           const float4* __restrict__ t0t,
                                           const float* __restrict__ wi,
                                           const float* __restrict__ wh0,
                                           const float* __restrict__ wh1,
                                           const float* __restrict__ bb,
                                           float wf0, float wf1, float bf)
{
    float h0, h1, c0, c1;   // c in scaled domain (c' = S2C * c_true)

    // ---- t = 0 via 1-D lerp table of x0 ----
    {
        float u = fmaf(xv.x, TMS, 256.0f);
        u = fminf(fmaxf(u, 0.0f), 511.0f);
        const float fl = floorf(u);
        const float fr = u - fl;
        const int j = (int)fl;
        const float4 a = t0t[j];
        const float4 b = t0t[j + 1];
        h0 = fmaf(fr, b.x - a.x, a.x);
        h1 = fmaf(fr, b.y - a.y, a.y);
        c0 = fmaf(fr, b.z - a.z, a.z);
        c1 = fmaf(fr, b.w - a.w, a.w);
    }

    // ---- t = 1..3 (R11 machinery, unchanged) ----
    const float xs[3] = {xv.y, xv.z, xv.w};
#pragma unroll
    for (int t = 0; t < 3; ++t) {
        const float xt = xs[t];
        const float p0 = fmaf(xt, wi[0], fmaf(h0, wh0[0], fmaf(h1, wh1[0], bb[0])));
        const float p1 = fmaf(xt, wi[1], fmaf(h0, wh0[1], fmaf(h1, wh1[1], bb[1])));
        const float p2 = fmaf(xt, wi[2], fmaf(h0, wh0[2], fmaf(h1, wh1[2], bb[2])));
        const float p3 = fmaf(xt, wi[3], fmaf(h0, wh0[3], fmaf(h1, wh1[3], bb[3])));
        const float p4 = fmaf(xt, wi[4], fmaf(h0, wh0[4], fmaf(h1, wh1[4], bb[4])));
        const float p5 = fmaf(xt, wi[5], fmaf(h0, wh0[5], fmaf(h1, wh1[5], bb[5])));
        const float p6 = fmaf(xt, wi[6], fmaf(h0, wh0[6], fmaf(h1, wh1[6], bb[6])));
        const float p7 = fmaf(xt, wi[7], fmaf(h0, wh0[7], fmaf(h1, wh1[7], bb[7])));
        const float I0 = SIG(p0), I1 = SIG(p1);
        const float F0 = SIG(p2), F1 = SIG(p3);
        const float O0 = SIG(p6), O1 = SIG(p7);
        const float e4 = fexp2(p4), e5 = fexp2(p5);
        const float dg0 = e4 + 1.f, dg1 = e5 + 1.f;
        const float rg = frcp(dg0 * dg1);
        const float G0 = fmaf(e4, S2C, -S2C) * (rg * dg1);  // S2C*tanh(g)
        const float G1 = fmaf(e5, S2C, -S2C) * (rg * dg0);
        c0 = fmaf(F0, c0, I0 * G0);
        c1 = fmaf(F1, c1, I1 * G1);
        const float ec0 = fexp2(c0), ec1 = fexp2(c1);
        const float td0 = ec0 + 1.f, td1 = ec1 + 1.f;
        const float rt = frcp(td0 * td1);
        h0 = O0 * ((ec0 - 1.f) * (rt * td1));
        h1 = O1 * ((ec1 - 1.f) * (rt * td0));
    }

    return fmaf(h0, wf0, fmaf(h1, wf1, bf));
}

__global__ __launch_bounds__(256) void lstm_main(
    const float4* __restrict__ x,   // [B] float4 per element
    const float*  __restrict__ ws,  // preprocessed constants + tables
    float2* __restrict__ out,       // [B/2]
    int B2)
{
    __shared__ __align__(16) float tbl[2048];      // sigmoid table, 8 KB
    __shared__ __align__(16) float4 t0t[514];      // t0 state table, ~8 KB
    const int tid = threadIdx.x;

    // cooperative load: sig 512 float4 + t0 513 float4
    {
        const float4* src = (const float4*)(ws + 64);
        float4* dst = (float4*)tbl;
        dst[tid]       = src[tid];
        dst[tid + 256] = src[tid + 256];
        t0t[tid]       = src[tid + 512];
        t0t[tid + 256] = src[tid + 768];
        if (tid == 0) t0t[512] = src[1024];
    }

    float wi[8], wh0[8], wh1[8], bb[8];
#pragma unroll
    for (int k = 0; k < 8; ++k) {
        wi[k] = ws[k]; wh0[k] = ws[8 + k]; wh1[k] = ws[16 + k]; bb[k] = ws[24 + k];
    }
    const float wf0 = ws[32], wf1 = ws[33], bf = ws[34];

    __syncthreads();

    const int idx = blockIdx.x * 256 + tid;
    if (idx >= B2) return;

    const float4 xa = x[2 * idx];
    const float4 xb = x[2 * idx + 1];

    const float oa = lstm_elem(xa, tbl, t0t, wi, wh0, wh1, bb, wf0, wf1, bf);
    const float ob = lstm_elem(xb, tbl, t0t, wi, wh0, wh1, bb, wf0, wf1, bf);

    float2 o; o.x = oa; o.y = ob;
    out[idx] = o;
}

extern "C" void kernel_launch(void* const* d_in, const int* in_sizes, int n_in,
                              void* d_out, int out_size, void* d_ws, size_t ws_size,
                              hipStream_t stream)
{
    const float* W_ih = (const float*)d_in[1];
    const float* W_hh = (const float*)d_in[2];
    const float* b_ih = (const float*)d_in[3];
    const float* b_hh = (const float*)d_in[4];
    const float* W_fc = (const float*)d_in[5];
    const float* b_fc = (const float*)d_in[6];
    float* ws = (float*)d_ws;

    lstm_prep<<<1, 256, 0, stream>>>(W_ih, W_hh, b_ih, b_hh, W_fc, b_fc, ws);

    const float4* x = (const float4*)d_in[0];
    float2* out = (float2*)d_out;
    const int B = in_sizes[0] / 4;   // 4194304
    const int B2 = B / 2;            // 2097152
    const int threads = 256;
    const int blocks = (B2 + threads - 1) / threads;   // 8192
    lstm_main<<<blocks, threads, 0, stream>>>(x, ws, out, B2);
}

// Round 14
// 32.922 us; speedup vs baseline: 1.1772x; 1.0304x over previous
//
#include <hip/hip_runtime.h>
#include <math.h>

// LSTM_8589935226: B=4194304 independent LSTMs, T=4, I=1, H=2, C=1.
// Round 14 = R13 + c-tanh via the SAME sigmoid table: tanh(c)=2*sig(2c)-1,
// idx = fma(c,256,1024.5) (c true-domain, |c|<=3.99 -> idx in [4,2046]).
// Removes 2 exp2 + 1 rcp + ~6V per step-elem for +2 lookups; trans/wave
// 36 -> 18. Issue -~160 cyc/wave; empirical wall ~= 2x issue -> ~30-32 us.
// g-gate stays exp2 (g->table would push DS to ~64/wave = R12 saturation).

__device__ __forceinline__ float fexp2(float x) { return __builtin_amdgcn_exp2f(x); }
__device__ __forceinline__ float frcp(float x)  { return __builtin_amdgcn_rcpf(x); }

#define S2C  2.8853900817779268f   // 2*log2(e)
#define TS   128.0f                // sig table scale
#define TOFF 1024.5f               // sig table center + nearest-round 0.5
// t0 table: 512 nodes over [-6.5, 6.5]; map u = x0*TMS + 256
#define TMS  39.384615384615387f   // 512/13

// ws float layout: [0..7] wi, [8..15] wh0, [16..23] wh1, [24..31] bb,
// [32..34] fc, [64..2111] sig table, [2112..4163] t0 table (513 float4,
// entry 512 duplicated so lerp j+1 read never overruns)
__global__ void lstm_prep(const float* __restrict__ W_ih,
                          const float* __restrict__ W_hh,
                          const float* __restrict__ b_ih,
                          const float* __restrict__ b_hh,
                          const float* __restrict__ W_fc,
                          const float* __restrict__ b_fc,
                          float* __restrict__ ws)
{
    const int k = threadIdx.x;
    if (k < 8) {
        // gate rows: i(0,1) f(2,3) g(4,5) o(6,7)
        if (k == 4 || k == 5) {        // g rows: exp2 path, scale 2*log2e
            ws[k]      = W_ih[k] * S2C;
            ws[8 + k]  = W_hh[2 * k] * S2C;
            ws[16 + k] = W_hh[2 * k + 1] * S2C;
            ws[24 + k] = (b_ih[k] + b_hh[k]) * S2C;
        } else {                       // sigmoid rows: table-map folded
            ws[k]      = W_ih[k] * TS;
            ws[8 + k]  = W_hh[2 * k] * TS;
            ws[16 + k] = W_hh[2 * k + 1] * TS;
            ws[24 + k] = (b_ih[k] + b_hh[k]) * TS + TOFF;
        }
    } else if (k == 8) {
        ws[32] = W_fc[0]; ws[33] = W_fc[1]; ws[34] = b_fc[0];
    }
    // sigmoid value table (also serves tanh: tanh(c) = 2*sig(2c)-1)
    for (int j = threadIdx.x; j < 2048; j += 256) {
        const float v = (float)(j - 1024) * (1.0f / 128.0f);  // [-8,8)
        ws[64 + j] = 1.0f / (1.0f + expf(-v));
    }
    // t0 state table: exact t=0 LSTM step as a function of x0 (c TRUE domain)
    for (int j = threadIdx.x; j < 513; j += 256) {
        const int jj = (j < 512) ? j : 512;
        const float x0 = -6.5f + (float)jj * (13.0f / 512.0f);
        float hh[2], cc[2];
        for (int q = 0; q < 2; ++q) {
            const float pi = W_ih[q]     * x0 + b_ih[q]     + b_hh[q];
            const float pg = W_ih[4 + q] * x0 + b_ih[4 + q] + b_hh[4 + q];
            const float po = W_ih[6 + q] * x0 + b_ih[6 + q] + b_hh[6 + q];
            const float I = 1.0f / (1.0f + expf(-pi));
            const float G = tanhf(pg);
            const float O = 1.0f / (1.0f + expf(-po));
            cc[q] = I * G;
            hh[q] = O * tanhf(cc[q]);
        }
        ws[2112 + 4 * j]     = hh[0];
        ws[2112 + 4 * j + 1] = hh[1];
        ws[2112 + 4 * j + 2] = cc[0];
        ws[2112 + 4 * j + 3] = cc[1];
    }
}

// sigmoid lookup: pre-act already carries the map (x128 + 1024.5)
#define SIG(p) tbl[(int)(p)]
// tanh(c) lookup through the same table: 2*sig(2c)-1; c true domain
#define TANHC(c) fmaf(tbl[(int)fmaf((c), 256.0f, TOFF)], 2.0f, -1.0f)

__device__ __forceinline__ float lstm_elem(const float4 xv,
                                           const float* __restrict__ tbl,
                                           const float4* __restrict__ t0t,
                                           const float* __restrict__ wi,
                                           const float* __restrict__ wh0,
                                           const float* __restrict__ wh1,
                                           const float* __restrict__ bb,
                                           float wf0, float wf1, float bf)
{
    float h0, h1, c0, c1;   // c in TRUE domain (|c| <= 3.99)

    // ---- t = 0 via 1-D lerp table of x0 ----
    {
        float u = fmaf(xv.x, TMS, 256.0f);
        u = fminf(fmaxf(u, 0.0f), 511.0f);
        const float fl = floorf(u);
        const float fr = u - fl;
        const int j = (int)fl;
        const float4 a = t0t[j];
        const float4 b = t0t[j + 1];
        h0 = fmaf(fr, b.x - a.x, a.x);
        h1 = fmaf(fr, b.y - a.y, a.y);
        c0 = fmaf(fr, b.z - a.z, a.z);
        c1 = fmaf(fr, b.w - a.w, a.w);
    }

    // ---- t = 1..3 ----
    const float xs[3] = {xv.y, xv.z, xv.w};
#pragma unroll
    for (int t = 0; t < 3; ++t) {
        const float xt = xs[t];
        const float p0 = fmaf(xt, wi[0], fmaf(h0, wh0[0], fmaf(h1, wh1[0], bb[0])));
        const float p1 = fmaf(xt, wi[1], fmaf(h0, wh0[1], fmaf(h1, wh1[1], bb[1])));
        const float p2 = fmaf(xt, wi[2], fmaf(h0, wh0[2], fmaf(h1, wh1[2], bb[2])));
        const float p3 = fmaf(xt, wi[3], fmaf(h0, wh0[3], fmaf(h1, wh1[3], bb[3])));
        const float p4 = fmaf(xt, wi[4], fmaf(h0, wh0[4], fmaf(h1, wh1[4], bb[4])));
        const float p5 = fmaf(xt, wi[5], fmaf(h0, wh0[5], fmaf(h1, wh1[5], bb[5])));
        const float p6 = fmaf(xt, wi[6], fmaf(h0, wh0[6], fmaf(h1, wh1[6], bb[6])));
        const float p7 = fmaf(xt, wi[7], fmaf(h0, wh0[7], fmaf(h1, wh1[7], bb[7])));
        const float I0 = SIG(p0), I1 = SIG(p1);
        const float F0 = SIG(p2), F1 = SIG(p3);
        const float O0 = SIG(p6), O1 = SIG(p7);
        // g gate: e = 2^(S2C*g_raw) = e^(2g) -> tanh(g) = (e-1)/(e+1)
        const float e4 = fexp2(p4), e5 = fexp2(p5);
        const float dg0 = e4 + 1.f, dg1 = e5 + 1.f;
        const float rg = frcp(dg0 * dg1);
        const float G0 = (e4 - 1.f) * (rg * dg1);
        const float G1 = (e5 - 1.f) * (rg * dg0);
        c0 = fmaf(F0, c0, I0 * G0);
        c1 = fmaf(F1, c1, I1 * G1);
        h0 = O0 * TANHC(c0);
        h1 = O1 * TANHC(c1);
    }

    return fmaf(h0, wf0, fmaf(h1, wf1, bf));
}

__global__ __launch_bounds__(256) void lstm_main(
    const float4* __restrict__ x,   // [B] float4 per element
    const float*  __restrict__ ws,  // preprocessed constants + tables
    float2* __restrict__ out,       // [B/2]
    int B2)
{
    __shared__ __align__(16) float tbl[2048];      // sigmoid table, 8 KB
    __shared__ __align__(16) float4 t0t[514];      // t0 state table, ~8 KB
    const int tid = threadIdx.x;

    // cooperative load: sig 512 float4 + t0 513 float4
    {
        const float4* src = (const float4*)(ws + 64);
        float4* dst = (float4*)tbl;
        dst[tid]       = src[tid];
        dst[tid + 256] = src[tid + 256];
        t0t[tid]       = src[tid + 512];
        t0t[tid + 256] = src[tid + 768];
        if (tid == 0) t0t[512] = src[1024];
    }

    float wi[8], wh0[8], wh1[8], bb[8];
#pragma unroll
    for (int k = 0; k < 8; ++k) {
        wi[k] = ws[k]; wh0[k] = ws[8 + k]; wh1[k] = ws[16 + k]; bb[k] = ws[24 + k];
    }
    const float wf0 = ws[32], wf1 = ws[33], bf = ws[34];

    __syncthreads();

    const int idx = blockIdx.x * 256 + tid;
    if (idx >= B2) return;

    const float4 xa = x[2 * idx];
    const float4 xb = x[2 * idx + 1];

    const float oa = lstm_elem(xa, tbl, t0t, wi, wh0, wh1, bb, wf0, wf1, bf);
    const float ob = lstm_elem(xb, tbl, t0t, wi, wh0, wh1, bb, wf0, wf1, bf);

    float2 o; o.x = oa; o.y = ob;
    out[idx] = o;
}

extern "C" void kernel_launch(void* const* d_in, const int* in_sizes, int n_in,
                              void* d_out, int out_size, void* d_ws, size_t ws_size,
                              hipStream_t stream)
{
    const float* W_ih = (const float*)d_in[1];
    const float* W_hh = (const float*)d_in[2];
    const float* b_ih = (const float*)d_in[3];
    const float* b_hh = (const float*)d_in[4];
    const float* W_fc = (const float*)d_in[5];
    const float* b_fc = (const float*)d_in[6];
    float* ws = (float*)d_ws;

    lstm_prep<<<1, 256, 0, stream>>>(W_ih, W_hh, b_ih, b_hh, W_fc, b_fc, ws);

    const float4* x = (const float4*)d_in[0];
    float2* out = (float2*)d_out;
    const int B = in_sizes[0] / 4;   // 4194304
    const int B2 = B / 2;            // 2097152
    const int threads = 256;
    const int blocks = (B2 + threads - 1) / threads;   // 8192
    lstm_main<<<blocks, threads, 0, stream>>>(x, ws, out, B2);
}